// Round 2
// baseline (811.576 us; speedup 1.0000x reference)
//
#include <hip/hip_runtime.h>
#include <hip/hip_bf16.h>

#define N_NODES 30000
#define N_EDGES 510000
#define K_DIM   128
#define ABLK    7500   // aggr node-blocks per snapshot (4 nodes/block)
#define EBLK    997    // edge-kernel blocks per snapshot: ceil(510000/512)

typedef short bf16x8 __attribute__((ext_vector_type(8)));
typedef float f32x4  __attribute__((ext_vector_type(4)));
typedef float f32x2  __attribute__((ext_vector_type(2)));
typedef unsigned int u32x2 __attribute__((ext_vector_type(2)));

__device__ __forceinline__ unsigned short f2bf(float f) {
  __hip_bfloat16 h = __float2bfloat16(f);
  return *(unsigned short*)&h;
}

// ---------------- both W transposes (K x M fp32) -> (M x K bf16) ----------------
__global__ void transpose_w_kernel(const float* __restrict__ W1, unsigned short* __restrict__ Wt1,
                                   const float* __restrict__ W2, unsigned short* __restrict__ Wt2) {
  int i = blockIdx.x * blockDim.x + threadIdx.x;
  if (i < 128 * 256) {
    int k = i >> 8, m = i & 255;
    Wt1[m * 128 + k] = f2bf(W1[i]);
  } else if (i < 128 * 256 + 128 * 128) {
    int j = i - 128 * 256;
    int k = j >> 7, m = j & 127;
    Wt2[m * 128 + k] = f2bf(W2[j]);
  }
}

// ---------------- degree for both snapshots ----------------
__global__ void deg_kernel(const int* __restrict__ ei, int* __restrict__ deg0,
                           int* __restrict__ deg1, int e) {
  int i = blockIdx.x * blockDim.x + threadIdx.x;
  if (i < 2 * e) {
    int t = i >= e ? 1 : 0;
    int j = i - t * e;
    int d = ei[(size_t)t * 2 * e + e + j];
    atomicAdd(&(t ? deg1 : deg0)[d], 1);
  }
}

// ---------------- exclusive scan (3-phase) + 1/deg, one block per snapshot ----------------
__global__ __launch_bounds__(1024) void scan_kernel(const int* __restrict__ deg0, int* __restrict__ off0,
                                                    int* __restrict__ cur0, float* __restrict__ rn0,
                                                    const int* __restrict__ deg1, int* __restrict__ off1,
                                                    int* __restrict__ cur1, float* __restrict__ rn1,
                                                    int n) {
  const int* deg = blockIdx.x ? deg1 : deg0;
  int* off = blockIdx.x ? off1 : off0;
  int* cur = blockIdx.x ? cur1 : cur0;
  float* rn = blockIdx.x ? rn1 : rn0;
  const int CHUNK = 30;  // 1024*30 >= 30000
  __shared__ int wsum[16];
  int tid = threadIdx.x;
  int base = tid * CHUNK;
  int sum = 0;
  for (int i = 0; i < CHUNK; i++)
    if (base + i < n) sum += deg[base + i];
  int lane = tid & 63, wid = tid >> 6;
  int incl = sum;
#pragma unroll
  for (int o = 1; o < 64; o <<= 1) {
    int v = __shfl_up(incl, o);
    if (lane >= o) incl += v;
  }
  if (lane == 63) wsum[wid] = incl;
  __syncthreads();
  if (tid == 0) {
    int run = 0;
    for (int w = 0; w < 16; w++) { int v = wsum[w]; wsum[w] = run; run += v; }
  }
  __syncthreads();
  int run = incl - sum + wsum[wid];
  for (int i = 0; i < CHUNK; i++) {
    if (base + i < n) {
      int dg = deg[base + i];
      off[base + i] = run;
      cur[base + i] = run;
      rn[base + i] = 1.0f / (float)dg;   // deg >= 1 (self-loop)
      run += dg;
    }
  }
}

// ---------------- scatter edges into CSR packed {src|dst<<16} for both snapshots ----------------
// src,dst < 30000 < 2^15, so u16 packing is exact.
__global__ void scatter_kernel(const int* __restrict__ ei,
                               int* __restrict__ cur0, int* __restrict__ cur1,
                               unsigned int* __restrict__ csr0, unsigned int* __restrict__ csr1, int e) {
  int i = blockIdx.x * blockDim.x + threadIdx.x;
  if (i < 2 * e) {
    int t = i >= e ? 1 : 0;
    int j = i - t * e;
    int s = ei[(size_t)t * 2 * e + j];
    int d = ei[(size_t)t * 2 * e + e + j];
    int* cur = t ? cur1 : cur0;
    unsigned int* csr = t ? csr1 : csr0;
    int p = atomicAdd(&cur[d], 1);
    csr[p] = (unsigned int)s | ((unsigned int)d << 16);
  }
}

// ---------------- fused GEMM + fp8-H write + per-node attention scores (both t) ----------------
template<int M, bool F32IN>
__global__ __launch_bounds__(256) void gemm_kernel(const void* __restrict__ X0v,
                                                   const void* __restrict__ X1v,
                                                   const short* __restrict__ Wt,
                                                   unsigned char* __restrict__ H0,
                                                   unsigned char* __restrict__ H1,
                                                   const float* __restrict__ att,
                                                   float* __restrict__ si0, float* __restrict__ si1,
                                                   float* __restrict__ sj0, float* __restrict__ sj1,
                                                   int nrows) {
  int t = blockIdx.y;
  const void* Xv = t ? X1v : X0v;
  unsigned char* Hf8 = t ? H1 : H0;
  float* s_i = t ? si1 : si0;
  float* s_j = t ? sj1 : sj0;

  int wave = blockIdx.x * 4 + (threadIdx.x >> 6);
  int lane = threadIdx.x & 63;
  if (wave * 16 >= nrows) return;
  int m16 = lane & 15, quad = lane >> 4;

  bf16x8 a[4];
  size_t arow = (size_t)(wave * 16 + m16) * K_DIM + quad * 8;
  if constexpr (F32IN) {
    const float* X = (const float*)Xv;
#pragma unroll
    for (int kc = 0; kc < 4; kc++) {
      f32x4 lo = *(const f32x4*)(X + arow + kc * 32);
      f32x4 hi = *(const f32x4*)(X + arow + kc * 32 + 4);
#pragma unroll
      for (int j = 0; j < 4; j++) {
        ((unsigned short*)&a[kc])[j]     = f2bf(lo[j]);
        ((unsigned short*)&a[kc])[4 + j] = f2bf(hi[j]);
      }
    }
  } else {
    const short* X = (const short*)Xv;
#pragma unroll
    for (int kc = 0; kc < 4; kc++) a[kc] = *(const bf16x8*)(X + arow + kc * 32);
  }

  float sip[4] = {0.f, 0.f, 0.f, 0.f}, sjp[4] = {0.f, 0.f, 0.f, 0.f};
#pragma unroll
  for (int nt = 0; nt < M / 16; nt++) {
    f32x4 acc = {0.f, 0.f, 0.f, 0.f};
    size_t brow = (size_t)(nt * 16 + m16) * K_DIM + quad * 8;
#pragma unroll
    for (int kc = 0; kc < 4; kc++) {
      bf16x8 b = *(const bf16x8*)(Wt + brow + kc * 32);
      acc = __builtin_amdgcn_mfma_f32_16x16x32_bf16(a[kc], b, acc, 0, 0, 0);
    }
    int col = nt * 16 + m16;
    float aA = att[col], aB = att[M + col];
#pragma unroll
    for (int r = 0; r < 4; r++) {
      int row = wave * 16 + quad * 4 + r;
      // hardware fp8 (OCP e4m3) convert — avoids software __hip_fp8 ctor path
      int pk = __builtin_amdgcn_cvt_pk_fp8_f32(acc[r], acc[r], 0, false);
      Hf8[(size_t)row * M + col] = (unsigned char)pk;
      sip[r] += acc[r] * aA;
      sjp[r] += acc[r] * aB;
    }
  }
#pragma unroll
  for (int o = 1; o < 16; o <<= 1) {
#pragma unroll
    for (int r = 0; r < 4; r++) {
      sip[r] += __shfl_xor(sip[r], o);
      sjp[r] += __shfl_xor(sjp[r], o);
    }
  }
  if (m16 == 0) {
#pragma unroll
    for (int r = 0; r < 4; r++) {
      int row = wave * 16 + quad * 4 + r;
      s_i[row] = sip[r];
      s_j[row] = sjp[r];
    }
  }
}

// ---------------- edge-parallel alpha precompute + skl partials ----------------
// Per CSR position: p = clip(sigmoid(leaky(si[dst]+sj[src]))), w = p/deg[dst],
// writes packed {src, w} (8B) consumed by aggr; skl accumulated per block.
__global__ __launch_bounds__(256) void edge_kernel(const unsigned int* __restrict__ csr_0,
                                                   const unsigned int* __restrict__ csr_1,
                                                   const float* __restrict__ rn0, const float* __restrict__ rn1,
                                                   const float* __restrict__ si0, const float* __restrict__ si1,
                                                   const float* __restrict__ sj0, const float* __restrict__ sj1,
                                                   u32x2* __restrict__ iw0, u32x2* __restrict__ iw1,
                                                   float* __restrict__ epart,  // [2*EBLK]
                                                   int e) {
  int t = blockIdx.y;
  const unsigned int* csr = t ? csr_1 : csr_0;
  const float* rn = t ? rn1 : rn0;
  const float* s_i = t ? si1 : si0;
  const float* s_j = t ? sj1 : sj0;
  u32x2* iw = t ? iw1 : iw0;

  const float q   = 1.0f / (1.0f + __expf(-(1.0f / 15.0f)));
  const float lq  = __logf(q);
  const float l1q = __logf(1.0f - q);

  __shared__ float red[4];
  float skl = 0.f;
  int p0 = (blockIdx.x * 256 + threadIdx.x) * 2;
#pragma unroll
  for (int u = 0; u < 2; u++) {
    int p = p0 + u;
    if (p < e) {
      unsigned int sd = csr[p];
      int s = (int)(sd & 0xffffu);
      int dd = (int)(sd >> 16);
      float lg = s_i[dd] + s_j[s];
      lg = lg > 0.f ? lg : 0.2f * lg;                 // leaky_relu
      float pv = 1.0f / (1.0f + __expf(-lg));        // sigmoid
      pv = fminf(fmaxf(pv, 0.01f), 0.99f);           // clip
      skl += pv * (__logf(pv) - lq) + (1.0f - pv) * (__logf(1.0f - pv) - l1q);
      float w = pv * rn[dd];                          // fold 1/deg into alpha
      u32x2 o;
      o[0] = (unsigned int)s;
      o[1] = __float_as_uint(w);
      iw[p] = o;
    }
  }
  int lane = threadIdx.x & 63, wid = threadIdx.x >> 6;
#pragma unroll
  for (int o = 32; o > 0; o >>= 1) skl += __shfl_xor(skl, o);
  if (lane == 0) red[wid] = skl;
  __syncthreads();
  if (threadIdx.x == 0) epart[t * EBLK + blockIdx.x] = red[0] + red[1] + red[2] + red[3];
}

// ---------------- per-node gather: precomputed {src,w}, 16B row loads, 2-deep pipeline ----------------
// 1D grid 2*ABLK, XCD-affine: t=0 blocks on XCDs 0-3, t=1 on 4-7 (halves per-XCD L2 working set).
// Single dependency level per chunk (iw -> H); hv/w ping-pong hides gather latency.
template<int M>  // M = 2C
__global__ __launch_bounds__(256) void aggr_kernel(const unsigned char* __restrict__ H0,
                                                   const unsigned char* __restrict__ H1,
                                                   const u32x2* __restrict__ iw0, const u32x2* __restrict__ iw1,
                                                   const int* __restrict__ off0, const int* __restrict__ off1,
                                                   const int* __restrict__ deg0, const int* __restrict__ deg1,
                                                   const float* __restrict__ bias,
                                                   float* __restrict__ mu0, float* __restrict__ mu1,
                                                   float* __restrict__ apart,  // [2*ABLK] ixz partials
                                                   int n) {
  constexpr int C = M / 2;
  constexpr int LPR = M / 16;                  // lanes per row (16B per lane)
  constexpr int L2LPR = (M == 256) ? 4 : 3;
  constexpr int EPL = 64 / LPR;                // edges per load instr: 4 / 8
  constexpr int U = 16;                        // edges per chunk
  constexpr int NL = U / EPL;                  // load instrs per chunk: 4 / 2

  int bid = blockIdx.x;                        // 0 .. 2*ABLK-1 (= 8*1875)
  int xcd = bid & 7;
  int t = xcd >> 2;
  int nb = (bid >> 3) * 4 + (xcd & 3);         // 0 .. ABLK-1, bijective

  const unsigned char* Hf8 = t ? H1 : H0;
  const u32x2* iw = t ? iw1 : iw0;
  const int* off = t ? off1 : off0;
  const int* deg = t ? deg1 : deg0;
  float* mu = t ? mu1 : mu0;

  __shared__ float red_i[4];
  int wid = threadIdx.x >> 6, lane = threadIdx.x & 63;
  int wave = nb * 4 + wid;
  float ixz = 0.f;

  if (wave < n) {
    int d     = __builtin_amdgcn_readfirstlane(deg[wave]);
    int start = __builtin_amdgcn_readfirstlane(off[wave]);
    const u32x2* iwp = iw + start;
    int sub = lane & (LPR - 1);
    int g   = lane >> L2LPR;                   // 0..EPL-1: which edge of the load
    int c0  = sub * 16;                        // 16 fp8 channels per lane
    const unsigned char* hbase = Hf8 + c0;

    f32x2 acc[8];
#pragma unroll
    for (int k = 0; k < 8; k++) acc[k] = {0.f, 0.f};

    u32x2 iwr[NL];
    uint4 hv0[NL], hv1[NL];
    float w0[NL], w1[NL];

    auto LOADIW = [&](int base) {
#pragma unroll
      for (int l = 0; l < NL; l++) {
        int e = base + l * EPL + g;
        e = e < d ? e : d - 1;                 // clamp (also covers prefetch past end)
        iwr[l] = iwp[e];
      }
    };
    auto ISSUE = [&](uint4* hv) {
#pragma unroll
      for (int l = 0; l < NL; l++)
        hv[l] = *(const uint4*)(hbase + (size_t)iwr[l][0] * M);
    };
    auto EXTW = [&](float* w, int base) {
#pragma unroll
      for (int l = 0; l < NL; l++) {
        int e = base + l * EPL + g;
        w[l] = (e < d) ? __uint_as_float(iwr[l][1]) : 0.f;
      }
    };
    auto FMA = [&](uint4* hv, float* w) {
#pragma unroll
      for (int l = 0; l < NL; l++) {
        f32x2 wv = {w[l], w[l]};
#pragma unroll
        for (int k = 0; k < 4; k++) {
          f32x2 lo = __builtin_amdgcn_cvt_pk_f32_fp8((int)hv[l][k], false);
          f32x2 hi = __builtin_amdgcn_cvt_pk_f32_fp8((int)hv[l][k], true);
          acc[2 * k]     = lo * wv + acc[2 * k];
          acc[2 * k + 1] = hi * wv + acc[2 * k + 1];
        }
      }
    };

    int nch = (d + U - 1) / U;
    LOADIW(0);
    ISSUE(hv0); EXTW(w0, 0);
    LOADIW(U);
    int c = 0;
    while (true) {
      if (c + 1 < nch) { ISSUE(hv1); EXTW(w1, (c + 1) * U); LOADIW((c + 2) * U); }
      FMA(hv0, w0);
      if (++c >= nch) break;
      if (c + 1 < nch) { ISSUE(hv0); EXTW(w0, (c + 1) * U); LOADIW((c + 2) * U); }
      FMA(hv1, w1);
      if (++c >= nch) break;
    }

    // combine lane-groups (same channels, different edges)
#pragma unroll
    for (int o = LPR; o < 64; o <<= 1) {
#pragma unroll
      for (int j = 0; j < 8; j++) {
        acc[j][0] += __shfl_xor(acc[j][0], o);
        acc[j][1] += __shfl_xor(acc[j][1], o);
      }
    }

    if (lane < LPR) {
      if (c0 < C) {
        f32x4 mv[4];
#pragma unroll
        for (int j = 0; j < 8; j++) {
          float a0 = acc[j][0] + bias[c0 + 2 * j];
          float a1 = acc[j][1] + bias[c0 + 2 * j + 1];
          ixz += 0.5f * (a0 * a0 + a1 * a1) - 1.0f;
          mv[j >> 1][(j & 1) * 2]     = a0;
          mv[j >> 1][(j & 1) * 2 + 1] = a1;
        }
#pragma unroll
        for (int k = 0; k < 4; k++)
          *(f32x4*)(mu + (size_t)wave * C + c0 + 4 * k) = mv[k];
      } else {
#pragma unroll
        for (int j = 0; j < 8; j++) {
#pragma unroll
          for (int h = 0; h < 2; h++) {
            float a = acc[j][h] + bias[c0 + 2 * j + h];
            float sp = (a > 20.f) ? a : log1pf(__expf(a));  // softplus
            sp += 1e-10f;
            ixz += -__logf(sp) + 0.5f * sp * sp;
          }
        }
      }
    }
  }
#pragma unroll
  for (int o = 32; o > 0; o >>= 1) ixz += __shfl_xor(ixz, o);
  if (lane == 0) red_i[wid] = ixz;
  __syncthreads();
  if (threadIdx.x == 0)
    apart[t * ABLK + nb] = red_i[0] + red_i[1] + red_i[2] + red_i[3];
}

// ---------------- layer-1 temporal fusion + ReLU -> bf16 layer-2 inputs ----------------
__global__ void fuse1_kernel(const float* __restrict__ mu0, const float* __restrict__ mu1,
                             __hip_bfloat16* __restrict__ x0, __hip_bfloat16* __restrict__ x1, int n) {
  int i = blockIdx.x * blockDim.x + threadIdx.x;
  if (i < n) {
    float m0 = mu0[i], m1 = mu1[i];
    x0[i] = __float2bfloat16(fmaxf(m0, 0.f));
    x1[i] = __float2bfloat16(fmaxf(0.4f * m0 + 0.2f * m1, 0.f));
  }
}

// ---------------- layer-2 temporal fusion -> final output (fp32) ----------------
__global__ void fuse2_kernel(const float* __restrict__ mu0, const float* __restrict__ mu1,
                             float* __restrict__ out, int n) {
  int i = blockIdx.x * blockDim.x + threadIdx.x;
  if (i < n) {
    float m0 = mu0[i], m1 = mu1[i];
    out[i] = m0;
    out[n + i] = 0.4f * m0 + 0.2f * m1;
  }
}

// ---------------- final reduction of per-block partials -> scalars ----------------
__global__ __launch_bounds__(1024) void reduce_kernel(const float* __restrict__ a1,
                                                      const float* __restrict__ a2,
                                                      const float* __restrict__ e1,
                                                      const float* __restrict__ e2,
                                                      float* __restrict__ out2) {
  __shared__ float ri[16], rs[16];
  float ixz = 0.f, skl = 0.f;
  for (int i = threadIdx.x; i < 2 * ABLK; i += 1024) ixz += a1[i] + a2[i];
  for (int i = threadIdx.x; i < 2 * EBLK; i += 1024) skl += e1[i] + e2[i];
  int lane = threadIdx.x & 63, wid = threadIdx.x >> 6;
#pragma unroll
  for (int o = 32; o > 0; o >>= 1) {
    ixz += __shfl_xor(ixz, o);
    skl += __shfl_xor(skl, o);
  }
  if (lane == 0) { ri[wid] = ixz; rs[wid] = skl; }
  __syncthreads();
  if (threadIdx.x == 0) {
    float si = 0.f, ss = 0.f;
    for (int w = 0; w < 16; w++) { si += ri[w]; ss += rs[w]; }
    out2[0] = si / (4.0f * (float)N_NODES);
    out2[1] = ss / (4.0f * (float)N_EDGES);
  }
}

extern "C" void kernel_launch(void* const* d_in, const int* in_sizes, int n_in,
                              void* d_out, int out_size, void* d_ws, size_t ws_size,
                              hipStream_t stream) {
  const float* x_all = (const float*)d_in[0];
  const int* ei      = (const int*)d_in[1];
  const float* W1    = (const float*)d_in[2];
  const float* att1  = (const float*)d_in[3];
  const float* b1    = (const float*)d_in[4];
  const float* W2    = (const float*)d_in[5];
  const float* att2  = (const float*)d_in[6];
  const float* b2    = (const float*)d_in[7];
  float* out         = (float*)d_out;

  char* ws = (char*)d_ws;
  size_t off = 0;
  auto alloc = [&](size_t bytes) {
    char* p = ws + off;
    off = (off + bytes + 255) & ~(size_t)255;
    return p;
  };
  unsigned short* wt1  = (unsigned short*)alloc(256 * 128 * sizeof(short));
  unsigned short* wt2  = (unsigned short*)alloc(128 * 128 * sizeof(short));
  unsigned char* hf8_0 = (unsigned char*)alloc((size_t)N_NODES * 256);
  unsigned char* hf8_1 = (unsigned char*)alloc((size_t)N_NODES * 256);
  float* si0   = (float*)alloc(N_NODES * sizeof(float));
  float* si1   = (float*)alloc(N_NODES * sizeof(float));
  float* sj0   = (float*)alloc(N_NODES * sizeof(float));
  float* sj1   = (float*)alloc(N_NODES * sizeof(float));
  float* mu1_0 = (float*)alloc((size_t)N_NODES * 128 * sizeof(float));
  float* mu1_1 = (float*)alloc((size_t)N_NODES * 128 * sizeof(float));
  // x2 region (2 x N*128 bf16 = 15.36 MB); iw buffers (2 x 4.08 MB) ALIAS it:
  //   edge1 writes iw -> aggr1 reads iw -> fuse1 writes x2 (iw dead) ->
  //   gemm2 reads x2 -> edge2 writes iw (x2 dead) -> aggr2 reads iw.  Stream-ordered.
  char* x2region = alloc((size_t)N_NODES * 256 * sizeof(short));
  __hip_bfloat16* x2_0 = (__hip_bfloat16*)x2region;
  __hip_bfloat16* x2_1 = x2_0 + (size_t)N_NODES * 128;
  u32x2* iwp[2] = {(u32x2*)x2region, (u32x2*)x2region + N_EDGES};
  // mu2 buffers alias mu1_0's region (mu1 dead after fuse1; stream-ordered)
  float* mu2_0 = mu1_0;
  float* mu2_1 = mu1_0 + (size_t)N_NODES * 64;
  int* degp[2]  = {(int*)alloc(N_NODES * 4), (int*)alloc(N_NODES * 4)};
  int* offp[2]  = {(int*)alloc(N_NODES * 4), (int*)alloc(N_NODES * 4)};
  int* curp[2]  = {(int*)alloc(N_NODES * 4), (int*)alloc(N_NODES * 4)};
  float* rnp[2] = {(float*)alloc(N_NODES * 4), (float*)alloc(N_NODES * 4)};
  unsigned int* csrp[2] = {(unsigned int*)alloc((size_t)N_EDGES * 4),
                           (unsigned int*)alloc((size_t)N_EDGES * 4)};
  float* apart1 = (float*)alloc(2 * ABLK * sizeof(float));
  float* apart2 = (float*)alloc(2 * ABLK * sizeof(float));
  float* epart1 = (float*)alloc(2 * EBLK * sizeof(float));
  float* epart2 = (float*)alloc(2 * EBLK * sizeof(float));

  hipMemsetAsync(degp[0], 0, N_NODES * 4, stream);
  hipMemsetAsync(degp[1], 0, N_NODES * 4, stream);

  transpose_w_kernel<<<192, 256, 0, stream>>>(W1, wt1, W2, wt2);

  deg_kernel<<<(2 * N_EDGES + 255) / 256, 256, 0, stream>>>(ei, degp[0], degp[1], N_EDGES);
  scan_kernel<<<2, 1024, 0, stream>>>(degp[0], offp[0], curp[0], rnp[0],
                                      degp[1], offp[1], curp[1], rnp[1], N_NODES);
  scatter_kernel<<<(2 * N_EDGES + 255) / 256, 256, 0, stream>>>(ei, curp[0], curp[1],
                                                                csrp[0], csrp[1], N_EDGES);

  dim3 ggrid(469, 2), egrid(EBLK, 2);

  // ---- layer 1 (C = 128, M = 256) ----
  const float* x0 = x_all;
  const float* x1 = x_all + (size_t)N_NODES * K_DIM;
  gemm_kernel<256, true><<<ggrid, 256, 0, stream>>>(x0, x1, (const short*)wt1, hf8_0, hf8_1,
                                                    att1, si0, si1, sj0, sj1, N_NODES);
  edge_kernel<<<egrid, 256, 0, stream>>>(csrp[0], csrp[1], rnp[0], rnp[1],
                                         si0, si1, sj0, sj1, iwp[0], iwp[1], epart1, N_EDGES);
  aggr_kernel<256><<<2 * ABLK, 256, 0, stream>>>(hf8_0, hf8_1, iwp[0], iwp[1], offp[0], offp[1],
                                                 degp[0], degp[1], b1, mu1_0, mu1_1, apart1, N_NODES);
  fuse1_kernel<<<(N_NODES * 128 + 255) / 256, 256, 0, stream>>>(mu1_0, mu1_1, x2_0, x2_1, N_NODES * 128);

  // ---- layer 2 (C = 64, M = 128) ----
  gemm_kernel<128, false><<<ggrid, 256, 0, stream>>>(x2_0, x2_1, (const short*)wt2, hf8_0, hf8_1,
                                                     att2, si0, si1, sj0, sj1, N_NODES);
  edge_kernel<<<egrid, 256, 0, stream>>>(csrp[0], csrp[1], rnp[0], rnp[1],
                                         si0, si1, sj0, sj1, iwp[0], iwp[1], epart2, N_EDGES);
  aggr_kernel<128><<<2 * ABLK, 256, 0, stream>>>(hf8_0, hf8_1, iwp[0], iwp[1], offp[0], offp[1],
                                                 degp[0], degp[1], b2, mu2_0, mu2_1, apart2, N_NODES);
  fuse2_kernel<<<(N_NODES * 64 + 255) / 256, 256, 0, stream>>>(mu2_0, mu2_1, out, N_NODES * 64);
  reduce_kernel<<<1, 1024, 0, stream>>>(apart1, apart2, epart1, epart2, out + (size_t)2 * N_NODES * 64);
}

// Round 3
// 599.134 us; speedup vs baseline: 1.3546x; 1.3546x over previous
//
#include <hip/hip_runtime.h>
#include <hip/hip_bf16.h>

#define N_NODES 30000
#define N_EDGES 510000
#define K_DIM   128
#define ABLK    7500   // aggr node-blocks per snapshot (4 nodes/block)
#define EBLK    997    // edge-kernel blocks per snapshot: ceil(510000/512)

typedef short bf16x8 __attribute__((ext_vector_type(8)));
typedef float f32x4  __attribute__((ext_vector_type(4)));
typedef float f32x2  __attribute__((ext_vector_type(2)));
typedef unsigned int u32x2 __attribute__((ext_vector_type(2)));

__device__ __forceinline__ unsigned short f2bf(float f) {
  __hip_bfloat16 h = __float2bfloat16(f);
  return *(unsigned short*)&h;
}

// ---------------- both W transposes (K x M fp32) -> (M x K bf16) ----------------
__global__ void transpose_w_kernel(const float* __restrict__ W1, unsigned short* __restrict__ Wt1,
                                   const float* __restrict__ W2, unsigned short* __restrict__ Wt2) {
  int i = blockIdx.x * blockDim.x + threadIdx.x;
  if (i < 128 * 256) {
    int k = i >> 8, m = i & 255;
    Wt1[m * 128 + k] = f2bf(W1[i]);
  } else if (i < 128 * 256 + 128 * 128) {
    int j = i - 128 * 256;
    int k = j >> 7, m = j & 127;
    Wt2[m * 128 + k] = f2bf(W2[j]);
  }
}

// ---------------- degree for both snapshots ----------------
__global__ void deg_kernel(const int* __restrict__ ei, int* __restrict__ deg0,
                           int* __restrict__ deg1, int e) {
  int i = blockIdx.x * blockDim.x + threadIdx.x;
  if (i < 2 * e) {
    int t = i >= e ? 1 : 0;
    int j = i - t * e;
    int d = ei[(size_t)t * 2 * e + e + j];
    atomicAdd(&(t ? deg1 : deg0)[d], 1);
  }
}

// ---------------- exclusive scan (3-phase) + 1/deg, one block per snapshot ----------------
__global__ __launch_bounds__(1024) void scan_kernel(const int* __restrict__ deg0, int* __restrict__ off0,
                                                    int* __restrict__ cur0, float* __restrict__ rn0,
                                                    const int* __restrict__ deg1, int* __restrict__ off1,
                                                    int* __restrict__ cur1, float* __restrict__ rn1,
                                                    int n) {
  const int* deg = blockIdx.x ? deg1 : deg0;
  int* off = blockIdx.x ? off1 : off0;
  int* cur = blockIdx.x ? cur1 : cur0;
  float* rn = blockIdx.x ? rn1 : rn0;
  const int CHUNK = 30;  // 1024*30 >= 30000
  __shared__ int wsum[16];
  int tid = threadIdx.x;
  int base = tid * CHUNK;
  int sum = 0;
  for (int i = 0; i < CHUNK; i++)
    if (base + i < n) sum += deg[base + i];
  int lane = tid & 63, wid = tid >> 6;
  int incl = sum;
#pragma unroll
  for (int o = 1; o < 64; o <<= 1) {
    int v = __shfl_up(incl, o);
    if (lane >= o) incl += v;
  }
  if (lane == 63) wsum[wid] = incl;
  __syncthreads();
  if (tid == 0) {
    int run = 0;
    for (int w = 0; w < 16; w++) { int v = wsum[w]; wsum[w] = run; run += v; }
  }
  __syncthreads();
  int run = incl - sum + wsum[wid];
  for (int i = 0; i < CHUNK; i++) {
    if (base + i < n) {
      int dg = deg[base + i];
      off[base + i] = run;
      cur[base + i] = run;
      rn[base + i] = 1.0f / (float)dg;   // deg >= 1 (self-loop)
      run += dg;
    }
  }
}

// ---------------- scatter edges into CSR packed {src|dst<<16} for both snapshots ----------------
// src,dst < 30000 < 2^15, so u16 packing is exact.
__global__ void scatter_kernel(const int* __restrict__ ei,
                               int* __restrict__ cur0, int* __restrict__ cur1,
                               unsigned int* __restrict__ csr0, unsigned int* __restrict__ csr1, int e) {
  int i = blockIdx.x * blockDim.x + threadIdx.x;
  if (i < 2 * e) {
    int t = i >= e ? 1 : 0;
    int j = i - t * e;
    int s = ei[(size_t)t * 2 * e + j];
    int d = ei[(size_t)t * 2 * e + e + j];
    int* cur = t ? cur1 : cur0;
    unsigned int* csr = t ? csr1 : csr0;
    int p = atomicAdd(&cur[d], 1);
    csr[p] = (unsigned int)s | ((unsigned int)d << 16);
  }
}

// ---------------- fused GEMM + fp8-H write + per-node attention scores (both t) ----------------
template<int M, bool F32IN>
__global__ __launch_bounds__(256) void gemm_kernel(const void* __restrict__ X0v,
                                                   const void* __restrict__ X1v,
                                                   const short* __restrict__ Wt,
                                                   unsigned char* __restrict__ H0,
                                                   unsigned char* __restrict__ H1,
                                                   const float* __restrict__ att,
                                                   float* __restrict__ si0, float* __restrict__ si1,
                                                   float* __restrict__ sj0, float* __restrict__ sj1,
                                                   int nrows) {
  int t = blockIdx.y;
  const void* Xv = t ? X1v : X0v;
  unsigned char* Hf8 = t ? H1 : H0;
  float* s_i = t ? si1 : si0;
  float* s_j = t ? sj1 : sj0;

  int wave = blockIdx.x * 4 + (threadIdx.x >> 6);
  int lane = threadIdx.x & 63;
  if (wave * 16 >= nrows) return;
  int m16 = lane & 15, quad = lane >> 4;

  bf16x8 a[4];
  size_t arow = (size_t)(wave * 16 + m16) * K_DIM + quad * 8;
  if constexpr (F32IN) {
    const float* X = (const float*)Xv;
#pragma unroll
    for (int kc = 0; kc < 4; kc++) {
      f32x4 lo = *(const f32x4*)(X + arow + kc * 32);
      f32x4 hi = *(const f32x4*)(X + arow + kc * 32 + 4);
#pragma unroll
      for (int j = 0; j < 4; j++) {
        ((unsigned short*)&a[kc])[j]     = f2bf(lo[j]);
        ((unsigned short*)&a[kc])[4 + j] = f2bf(hi[j]);
      }
    }
  } else {
    const short* X = (const short*)Xv;
#pragma unroll
    for (int kc = 0; kc < 4; kc++) a[kc] = *(const bf16x8*)(X + arow + kc * 32);
  }

  float sip[4] = {0.f, 0.f, 0.f, 0.f}, sjp[4] = {0.f, 0.f, 0.f, 0.f};
#pragma unroll
  for (int nt = 0; nt < M / 16; nt++) {
    f32x4 acc = {0.f, 0.f, 0.f, 0.f};
    size_t brow = (size_t)(nt * 16 + m16) * K_DIM + quad * 8;
#pragma unroll
    for (int kc = 0; kc < 4; kc++) {
      bf16x8 b = *(const bf16x8*)(Wt + brow + kc * 32);
      acc = __builtin_amdgcn_mfma_f32_16x16x32_bf16(a[kc], b, acc, 0, 0, 0);
    }
    int col = nt * 16 + m16;
    float aA = att[col], aB = att[M + col];
#pragma unroll
    for (int r = 0; r < 4; r++) {
      int row = wave * 16 + quad * 4 + r;
      // hardware fp8 (OCP e4m3) convert — avoids software __hip_fp8 ctor path
      int pk = __builtin_amdgcn_cvt_pk_fp8_f32(acc[r], acc[r], 0, false);
      Hf8[(size_t)row * M + col] = (unsigned char)pk;
      sip[r] += acc[r] * aA;
      sjp[r] += acc[r] * aB;
    }
  }
#pragma unroll
  for (int o = 1; o < 16; o <<= 1) {
#pragma unroll
    for (int r = 0; r < 4; r++) {
      sip[r] += __shfl_xor(sip[r], o);
      sjp[r] += __shfl_xor(sjp[r], o);
    }
  }
  if (m16 == 0) {
#pragma unroll
    for (int r = 0; r < 4; r++) {
      int row = wave * 16 + quad * 4 + r;
      s_i[row] = sip[r];
      s_j[row] = sjp[r];
    }
  }
}

// ---------------- edge-parallel alpha precompute + skl partials ----------------
// Per CSR position: p = clip(sigmoid(leaky(si[dst]+sj[src]))), w = p/deg[dst],
// writes packed {src, w} (8B) consumed by aggr; skl accumulated per block.
__global__ __launch_bounds__(256) void edge_kernel(const unsigned int* __restrict__ csr_0,
                                                   const unsigned int* __restrict__ csr_1,
                                                   const float* __restrict__ rn0, const float* __restrict__ rn1,
                                                   const float* __restrict__ si0, const float* __restrict__ si1,
                                                   const float* __restrict__ sj0, const float* __restrict__ sj1,
                                                   u32x2* __restrict__ iw0, u32x2* __restrict__ iw1,
                                                   float* __restrict__ epart,  // [2*EBLK]
                                                   int e) {
  int t = blockIdx.y;
  const unsigned int* csr = t ? csr_1 : csr_0;
  const float* rn = t ? rn1 : rn0;
  const float* s_i = t ? si1 : si0;
  const float* s_j = t ? sj1 : sj0;
  u32x2* iw = t ? iw1 : iw0;

  const float q   = 1.0f / (1.0f + __expf(-(1.0f / 15.0f)));
  const float lq  = __logf(q);
  const float l1q = __logf(1.0f - q);

  __shared__ float red[4];
  float skl = 0.f;
  int p0 = (blockIdx.x * 256 + threadIdx.x) * 2;
#pragma unroll
  for (int u = 0; u < 2; u++) {
    int p = p0 + u;
    if (p < e) {
      unsigned int sd = csr[p];
      int s = (int)(sd & 0xffffu);
      int dd = (int)(sd >> 16);
      float lg = s_i[dd] + s_j[s];
      lg = lg > 0.f ? lg : 0.2f * lg;                 // leaky_relu
      float pv = 1.0f / (1.0f + __expf(-lg));        // sigmoid
      pv = fminf(fmaxf(pv, 0.01f), 0.99f);           // clip
      skl += pv * (__logf(pv) - lq) + (1.0f - pv) * (__logf(1.0f - pv) - l1q);
      float w = pv * rn[dd];                          // fold 1/deg into alpha
      u32x2 o;
      o[0] = (unsigned int)s;
      o[1] = __float_as_uint(w);
      iw[p] = o;
    }
  }
  int lane = threadIdx.x & 63, wid = threadIdx.x >> 6;
#pragma unroll
  for (int o = 32; o > 0; o >>= 1) skl += __shfl_xor(skl, o);
  if (lane == 0) red[wid] = skl;
  __syncthreads();
  if (threadIdx.x == 0) epart[t * EBLK + blockIdx.x] = red[0] + red[1] + red[2] + red[3];
}

// ---------------- per-node gather: R0 memory structure + precomputed {src,w} ----------------
// One wave per node; 8B u32x2 row loads (LPR lanes/row); serial chunk body; plain
// arrays only in fully-unrolled literal-index loops (R0-proven codegen: low VGPR).
template<int M>  // M = 2C
__global__ __launch_bounds__(256) void aggr_kernel(const unsigned char* __restrict__ H0,
                                                   const unsigned char* __restrict__ H1,
                                                   const u32x2* __restrict__ iw0, const u32x2* __restrict__ iw1,
                                                   const int* __restrict__ off0, const int* __restrict__ off1,
                                                   const int* __restrict__ deg0, const int* __restrict__ deg1,
                                                   const float* __restrict__ bias,
                                                   float* __restrict__ mu0, float* __restrict__ mu1,
                                                   float* __restrict__ apart,  // [2*ABLK] ixz partials
                                                   int n) {
  constexpr int C = M / 2;
  constexpr int LPR = M / 8;                   // lanes per row (8B per lane): 32 / 16
  constexpr int L2LPR = (M == 256) ? 5 : 4;
  constexpr int EPL = 64 / LPR;                // edges per load instr: 2 / 4
  constexpr int NL = 4;                        // loads per chunk
  constexpr int U = NL * EPL;                  // edges per chunk: 8 / 16

  int t = blockIdx.y;
  const unsigned char* Hf8 = t ? H1 : H0;
  const u32x2* iw = t ? iw1 : iw0;
  const int* off = t ? off1 : off0;
  const int* deg = t ? deg1 : deg0;
  float* mu = t ? mu1 : mu0;

  __shared__ float red_i[4];
  int wid = threadIdx.x >> 6, lane = threadIdx.x & 63;
  int wave = blockIdx.x * 4 + wid;
  float ixz = 0.f;

  if (wave < n) {
    int d     = __builtin_amdgcn_readfirstlane(deg[wave]);
    int start = __builtin_amdgcn_readfirstlane(off[wave]);
    const u32x2* iwp = iw + start;
    int sub = lane & (LPR - 1);
    int g   = lane >> L2LPR;                   // which edge within a load instr
    int c0  = sub * 8;                         // 8 fp8 channels per lane
    const unsigned char* hbase = Hf8 + c0;

    f32x2 acc[4];
#pragma unroll
    for (int k = 0; k < 4; k++) acc[k] = {0.f, 0.f};

    for (int e0 = 0; e0 < d; e0 += U) {
      // per-lane direct iw loads (broadcast within LPR-lane groups)
      u32x2 iwl[NL];
      float wl[NL];
#pragma unroll
      for (int l = 0; l < NL; l++) {
        int e = e0 + l * EPL + g;
        iwl[l] = iwp[e < d ? e : d - 1];       // clamped, always-valid
      }
#pragma unroll
      for (int l = 0; l < NL; l++) {
        int e = e0 + l * EPL + g;
        wl[l] = (e < d) ? __uint_as_float(iwl[l][1]) : 0.f;
      }
      // packed row gathers: NL loads, EPL edges each
      u32x2 hv[NL];
#pragma unroll
      for (int l = 0; l < NL; l++)
        hv[l] = *(const u32x2*)(hbase + (size_t)iwl[l][0] * M);
      // packed fp8 -> f32 decode + pk-FMA
#pragma unroll
      for (int l = 0; l < NL; l++) {
        f32x2 wv = {wl[l], wl[l]};
        f32x2 d0 = __builtin_amdgcn_cvt_pk_f32_fp8((int)hv[l][0], false);
        f32x2 d1 = __builtin_amdgcn_cvt_pk_f32_fp8((int)hv[l][0], true);
        f32x2 d2 = __builtin_amdgcn_cvt_pk_f32_fp8((int)hv[l][1], false);
        f32x2 d3 = __builtin_amdgcn_cvt_pk_f32_fp8((int)hv[l][1], true);
        acc[0] = d0 * wv + acc[0];
        acc[1] = d1 * wv + acc[1];
        acc[2] = d2 * wv + acc[2];
        acc[3] = d3 * wv + acc[3];
      }
    }

    // combine lane-groups (same channels, different edges)
#pragma unroll
    for (int o = LPR; o < 64; o <<= 1) {
#pragma unroll
      for (int j = 0; j < 4; j++) {
        acc[j][0] += __shfl_xor(acc[j][0], o);
        acc[j][1] += __shfl_xor(acc[j][1], o);
      }
    }

    if (lane < LPR) {
      if (c0 < C) {
        f32x4 m0, m1;
#pragma unroll
        for (int j = 0; j < 4; j++) {
          float a0 = acc[j][0] + bias[c0 + 2 * j];
          float a1 = acc[j][1] + bias[c0 + 2 * j + 1];
          ixz += 0.5f * (a0 * a0 + a1 * a1) - 1.0f;
          ((float*)&m0)[2 * j]     = a0;   // j<2 -> m0, j>=2 -> m1 handled below
          ((float*)&m0)[2 * j + 1] = a1;
        }
        // note: loop above filled 8 floats contiguously starting at m0
        *(f32x4*)(mu + (size_t)wave * C + c0)     = *(f32x4*)&m0;
        *(f32x4*)(mu + (size_t)wave * C + c0 + 4) = *((f32x4*)&m0 + 1);
        (void)m1;
      } else {
#pragma unroll
        for (int j = 0; j < 4; j++) {
#pragma unroll
          for (int h = 0; h < 2; h++) {
            float a = acc[j][h] + bias[c0 + 2 * j + h];
            float sp = (a > 20.f) ? a : log1pf(__expf(a));  // softplus
            sp += 1e-10f;
            ixz += -__logf(sp) + 0.5f * sp * sp;
          }
        }
      }
    }
  }
#pragma unroll
  for (int o = 32; o > 0; o >>= 1) ixz += __shfl_xor(ixz, o);
  if (lane == 0) red_i[wid] = ixz;
  __syncthreads();
  if (threadIdx.x == 0)
    apart[t * ABLK + blockIdx.x] = red_i[0] + red_i[1] + red_i[2] + red_i[3];
}

// ---------------- layer-1 temporal fusion + ReLU -> bf16 layer-2 inputs ----------------
__global__ void fuse1_kernel(const float* __restrict__ mu0, const float* __restrict__ mu1,
                             __hip_bfloat16* __restrict__ x0, __hip_bfloat16* __restrict__ x1, int n) {
  int i = blockIdx.x * blockDim.x + threadIdx.x;
  if (i < n) {
    float m0 = mu0[i], m1 = mu1[i];
    x0[i] = __float2bfloat16(fmaxf(m0, 0.f));
    x1[i] = __float2bfloat16(fmaxf(0.4f * m0 + 0.2f * m1, 0.f));
  }
}

// ---------------- layer-2 temporal fusion -> final output (fp32) ----------------
__global__ void fuse2_kernel(const float* __restrict__ mu0, const float* __restrict__ mu1,
                             float* __restrict__ out, int n) {
  int i = blockIdx.x * blockDim.x + threadIdx.x;
  if (i < n) {
    float m0 = mu0[i], m1 = mu1[i];
    out[i] = m0;
    out[n + i] = 0.4f * m0 + 0.2f * m1;
  }
}

// ---------------- final reduction of per-block partials -> scalars ----------------
__global__ __launch_bounds__(1024) void reduce_kernel(const float* __restrict__ a1,
                                                      const float* __restrict__ a2,
                                                      const float* __restrict__ e1,
                                                      const float* __restrict__ e2,
                                                      float* __restrict__ out2) {
  __shared__ float ri[16], rs[16];
  float ixz = 0.f, skl = 0.f;
  for (int i = threadIdx.x; i < 2 * ABLK; i += 1024) ixz += a1[i] + a2[i];
  for (int i = threadIdx.x; i < 2 * EBLK; i += 1024) skl += e1[i] + e2[i];
  int lane = threadIdx.x & 63, wid = threadIdx.x >> 6;
#pragma unroll
  for (int o = 32; o > 0; o >>= 1) {
    ixz += __shfl_xor(ixz, o);
    skl += __shfl_xor(skl, o);
  }
  if (lane == 0) { ri[wid] = ixz; rs[wid] = skl; }
  __syncthreads();
  if (threadIdx.x == 0) {
    float si = 0.f, ss = 0.f;
    for (int w = 0; w < 16; w++) { si += ri[w]; ss += rs[w]; }
    out2[0] = si / (4.0f * (float)N_NODES);
    out2[1] = ss / (4.0f * (float)N_EDGES);
  }
}

extern "C" void kernel_launch(void* const* d_in, const int* in_sizes, int n_in,
                              void* d_out, int out_size, void* d_ws, size_t ws_size,
                              hipStream_t stream) {
  const float* x_all = (const float*)d_in[0];
  const int* ei      = (const int*)d_in[1];
  const float* W1    = (const float*)d_in[2];
  const float* att1  = (const float*)d_in[3];
  const float* b1    = (const float*)d_in[4];
  const float* W2    = (const float*)d_in[5];
  const float* att2  = (const float*)d_in[6];
  const float* b2    = (const float*)d_in[7];
  float* out         = (float*)d_out;

  char* ws = (char*)d_ws;
  size_t off = 0;
  auto alloc = [&](size_t bytes) {
    char* p = ws + off;
    off = (off + bytes + 255) & ~(size_t)255;
    return p;
  };
  unsigned short* wt1  = (unsigned short*)alloc(256 * 128 * sizeof(short));
  unsigned short* wt2  = (unsigned short*)alloc(128 * 128 * sizeof(short));
  unsigned char* hf8_0 = (unsigned char*)alloc((size_t)N_NODES * 256);
  unsigned char* hf8_1 = (unsigned char*)alloc((size_t)N_NODES * 256);
  float* si0   = (float*)alloc(N_NODES * sizeof(float));
  float* si1   = (float*)alloc(N_NODES * sizeof(float));
  float* sj0   = (float*)alloc(N_NODES * sizeof(float));
  float* sj1   = (float*)alloc(N_NODES * sizeof(float));
  float* mu1_0 = (float*)alloc((size_t)N_NODES * 128 * sizeof(float));
  float* mu1_1 = (float*)alloc((size_t)N_NODES * 128 * sizeof(float));
  // x2 region (2 x N*128 bf16 = 15.36 MB); iw buffers (2 x 4.08 MB) ALIAS it:
  //   edge1 writes iw -> aggr1 reads iw -> fuse1 writes x2 (iw dead) ->
  //   gemm2 reads x2 -> edge2 writes iw (x2 dead) -> aggr2 reads iw.  Stream-ordered.
  char* x2region = alloc((size_t)N_NODES * 256 * sizeof(short));
  __hip_bfloat16* x2_0 = (__hip_bfloat16*)x2region;
  __hip_bfloat16* x2_1 = x2_0 + (size_t)N_NODES * 128;
  u32x2* iwp[2] = {(u32x2*)x2region, (u32x2*)x2region + N_EDGES};
  // mu2 buffers alias mu1_0's region (mu1 dead after fuse1; stream-ordered)
  float* mu2_0 = mu1_0;
  float* mu2_1 = mu1_0 + (size_t)N_NODES * 64;
  int* degp[2]  = {(int*)alloc(N_NODES * 4), (int*)alloc(N_NODES * 4)};
  int* offp[2]  = {(int*)alloc(N_NODES * 4), (int*)alloc(N_NODES * 4)};
  int* curp[2]  = {(int*)alloc(N_NODES * 4), (int*)alloc(N_NODES * 4)};
  float* rnp[2] = {(float*)alloc(N_NODES * 4), (float*)alloc(N_NODES * 4)};
  unsigned int* csrp[2] = {(unsigned int*)alloc((size_t)N_EDGES * 4),
                           (unsigned int*)alloc((size_t)N_EDGES * 4)};
  float* apart1 = (float*)alloc(2 * ABLK * sizeof(float));
  float* apart2 = (float*)alloc(2 * ABLK * sizeof(float));
  float* epart1 = (float*)alloc(2 * EBLK * sizeof(float));
  float* epart2 = (float*)alloc(2 * EBLK * sizeof(float));

  hipMemsetAsync(degp[0], 0, N_NODES * 4, stream);
  hipMemsetAsync(degp[1], 0, N_NODES * 4, stream);

  transpose_w_kernel<<<192, 256, 0, stream>>>(W1, wt1, W2, wt2);

  deg_kernel<<<(2 * N_EDGES + 255) / 256, 256, 0, stream>>>(ei, degp[0], degp[1], N_EDGES);
  scan_kernel<<<2, 1024, 0, stream>>>(degp[0], offp[0], curp[0], rnp[0],
                                      degp[1], offp[1], curp[1], rnp[1], N_NODES);
  scatter_kernel<<<(2 * N_EDGES + 255) / 256, 256, 0, stream>>>(ei, curp[0], curp[1],
                                                                csrp[0], csrp[1], N_EDGES);

  dim3 ggrid(469, 2), egrid(EBLK, 2), agrid(ABLK, 2);

  // ---- layer 1 (C = 128, M = 256) ----
  const float* x0 = x_all;
  const float* x1 = x_all + (size_t)N_NODES * K_DIM;
  gemm_kernel<256, true><<<ggrid, 256, 0, stream>>>(x0, x1, (const short*)wt1, hf8_0, hf8_1,
                                                    att1, si0, si1, sj0, sj1, N_NODES);
  edge_kernel<<<egrid, 256, 0, stream>>>(csrp[0], csrp[1], rnp[0], rnp[1],
                                         si0, si1, sj0, sj1, iwp[0], iwp[1], epart1, N_EDGES);
  aggr_kernel<256><<<agrid, 256, 0, stream>>>(hf8_0, hf8_1, iwp[0], iwp[1], offp[0], offp[1],
                                              degp[0], degp[1], b1, mu1_0, mu1_1, apart1, N_NODES);
  fuse1_kernel<<<(N_NODES * 128 + 255) / 256, 256, 0, stream>>>(mu1_0, mu1_1, x2_0, x2_1, N_NODES * 128);

  // ---- layer 2 (C = 64, M = 128) ----
  gemm_kernel<128, false><<<ggrid, 256, 0, stream>>>(x2_0, x2_1, (const short*)wt2, hf8_0, hf8_1,
                                                     att2, si0, si1, sj0, sj1, N_NODES);
  edge_kernel<<<egrid, 256, 0, stream>>>(csrp[0], csrp[1], rnp[0], rnp[1],
                                         si0, si1, sj0, sj1, iwp[0], iwp[1], epart2, N_EDGES);
  aggr_kernel<128><<<agrid, 256, 0, stream>>>(hf8_0, hf8_1, iwp[0], iwp[1], offp[0], offp[1],
                                              degp[0], degp[1], b2, mu2_0, mu2_1, apart2, N_NODES);
  fuse2_kernel<<<(N_NODES * 64 + 255) / 256, 256, 0, stream>>>(mu2_0, mu2_1, out, N_NODES * 64);
  reduce_kernel<<<1, 1024, 0, stream>>>(apart1, apart2, epart1, epart2, out + (size_t)2 * N_NODES * 64);
}